// Round 7
// baseline (319.929 us; speedup 1.0000x reference)
//
#include <hip/hip_runtime.h>

#define BB 32
#define NN 1024
#define HH 512
#define NS 1023   // S length per row

typedef unsigned short u16;
typedef unsigned int   u32;
typedef __attribute__((ext_vector_type(8))) short bf16x8;
typedef __attribute__((ext_vector_type(4))) float f32x4;

__device__ __forceinline__ float bf2f(u16 h) {
  union { u32 u; float f; } c; c.u = ((u32)h) << 16; return c.f;
}
__device__ __forceinline__ u16 f2bf(float f) {
  union { float f; u32 u; } c; c.f = f;
  u32 u = c.u;
  return (u16)((u + 0x7fffu + ((u >> 16) & 1u)) >> 16);
}
// split x = hi + lo (each bf16); residual ~2^-18 relative
__device__ __forceinline__ void split_bf(float x, u16& hi, u16& lo) {
  hi = f2bf(x);
  lo = f2bf(x - bf2f(hi));
}
// async global->LDS DMA, 16 B per lane; LDS dest = wave-uniform base + lane*16
__device__ __forceinline__ void dma16(const u16* g, u16* l) {
  __builtin_amdgcn_global_load_lds(
      (const __attribute__((address_space(1))) u32*)g,
      (__attribute__((address_space(3))) u32*)l, 16, 0, 0);
}

// ---------------------------------------------------------------- prep A
// 256 threads = 4 waves, one row per wave
__global__ __launch_bounds__(256) void k_prep_a(const float* __restrict__ seg,
                                                u16* __restrict__ ahi,
                                                u16* __restrict__ alo) {
  int row = blockIdx.x * 4 + (threadIdx.x >> 6);
  int lane = threadIdx.x & 63;
  const float4* p = (const float4*)(seg + ((size_t)row << 9) + lane * 8);
  float4 a = p[0], b = p[1];
  float v[8] = {a.x, a.y, a.z, a.w, b.x, b.y, b.z, b.w};
  float s = 0.f;
#pragma unroll
  for (int i = 0; i < 8; ++i) s += v[i] * v[i];
#pragma unroll
  for (int m = 32; m; m >>= 1) s += __shfl_xor(s, m, 64);
  float nrm = sqrtf(s);
  u16 h[8], l[8];
#pragma unroll
  for (int i = 0; i < 8; ++i) split_bf(v[i] / nrm, h[i], l[i]);
  size_t off = ((size_t)row << 9) + lane * 8;
  *(uint4*)(ahi + off) = make_uint4(h[0] | (h[1] << 16), h[2] | (h[3] << 16),
                                    h[4] | (h[5] << 16), h[6] | (h[7] << 16));
  *(uint4*)(alo + off) = make_uint4(l[0] | (l[1] << 16), l[2] | (l[3] << 16),
                                    l[4] | (l[5] << 16), l[6] | (l[7] << 16));
}

// ---------------------------------------------------------------- transpose-split
// merged: z=0 -> W1 (K=1024), z=1 -> We1, z=2 -> We2 (K=512, y<8 only)
__global__ __launch_bounds__(256) void k_tr3(const float* __restrict__ W1,
                                             const float* __restrict__ We1,
                                             const float* __restrict__ We2,
                                             u16* __restrict__ w1h,
                                             u16* __restrict__ w1l,
                                             u16* __restrict__ we1t,
                                             u16* __restrict__ we2t) {
  __shared__ u16 Th[64 * 66], Tl[64 * 66];
  int z = blockIdx.z;
  const float* src; u16 *dh, *dl; int K, N;
  if (z == 0)      { src = W1;  dh = w1h;  dl = w1l;          K = 1024; N = 512; }
  else if (z == 1) { src = We1; dh = we1t; dl = (u16*)0;      K = 512;  N = 512; }
  else             { src = We2; dh = we2t; dl = (u16*)0;      K = 512;  N = 512; }
  if (blockIdx.y * 64 >= K) return;   // uniform per block, before any barrier
  int nb = blockIdx.x * 64, kb = blockIdx.y * 64;
  int tid = threadIdx.x;
#pragma unroll
  for (int i = 0; i < 16; ++i) {
    int e = tid + i * 256;
    int r = e >> 6, c = e & 63;
    float v = src[(size_t)(kb + r) * N + nb + c];
    u16 hi, lo; split_bf(v, hi, lo);
    Th[c * 66 + r] = hi;
    Tl[c * 66 + r] = lo;
  }
  __syncthreads();
#pragma unroll
  for (int i = 0; i < 16; ++i) {
    int e = tid + i * 256;
    int n = e >> 6, k = e & 63;
    dh[(size_t)(nb + n) * K + kb + k] = Th[n * 66 + k];
    if (dl) dl[(size_t)(nb + n) * K + kb + k] = Tl[n * 66 + k];
  }
}

// ---------------------------------------------------------------- S-GEMM (MFMA)
// 256m x 256n block, BK=32, 8 waves (2m x 4n), wave tile 128x64.
// XCD-twin remap (round-3 win): 1-D grid 256, nblk twins of each mblk on the
// same XCD -> A fetched ~once from HBM (FETCH 74 MB, verified round 4).
// v7 schedule: 3-phase counted skeleton (round-4, 86 us) + READS TRAIL MFMA:
// each phase's MFMA consumes registers loaded in the PREVIOUS phase, and its
// tail issues the ds_reads for the NEXT phase. The LDS-read pipe (~2500
// cyc/step incl conflicts) thus overlaps the MFMA pipe (~3700 cyc/step)
// instead of serializing (6400 cyc measured at 86 us). lgkmcnt(0) fences are
// free (loads issued a full phase + barrier earlier); all loads are
// compiler-visible so no counted-lgkm fragility. vmcnt dma accounting per
// wave: entry [AL(ks)]=2; ph0 +AH,BH -> vmcnt(4) drains AL(ks); ph1 +BL,AL
// -> vmcnt(4) drains AH,BH(ks+1); ph2 vmcnt(2) drains BL(ks+1).
// Register ping-pong (ahA/bhA <-> ahB/bhB) via 2-step unroll.
// Per-accumulator MFMA order (hh, hl, lh per tile) unchanged -> bit-exact.
__global__ __launch_bounds__(512, 2) void k_sgemm(const u16* __restrict__ ahi,
                                                  const u16* __restrict__ alo,
                                                  const u16* __restrict__ w1h,
                                                  const u16* __restrict__ w1l,
                                                  const float* __restrict__ b1,
                                                  const float* __restrict__ W2,
                                                  float* __restrict__ Spart) {
  __shared__ u16 Ah[2][256 * 32];   // 32 KB
  __shared__ u16 Al[2][256 * 32];   // 32 KB
  __shared__ u16 Bh[2][256 * 32];   // 32 KB
  __shared__ u16 Bl[2][256 * 32];   // 32 KB   (total 128 KiB)

  const int tid  = threadIdx.x;
  const int wave = tid >> 6, lane = tid & 63;
  const int quad = lane >> 4, l15 = lane & 15;
  const int wm = wave >> 2, wn = wave & 3;
  const int r_in = lane >> 2, c_in = lane & 3;   // DMA chunk coords
  const int w    = blockIdx.x;                   // 0..255
  const int xcd  = w & 7, slot = w >> 3;
  const int nblk = slot & 1;
  const int mblk = xcd * 16 + (slot >> 1);
  const int mrow0 = mblk * 256;
  const int ncol0 = nblk * 256;

#define SG_AH(tb_, ks_)                                                      \
  {                                                                          \
    int k0_ = (ks_) * 32, half_ = k0_ >> 9, cb_ = k0_ & 511;                 \
    int g0_ = mrow0 + wave * 32 + r_in + half_;                              \
    int g1_ = g0_ + 16;                                                      \
    if (g0_ > 32767) g0_ = 32767;                                            \
    if (g1_ > 32767) g1_ = 32767;                                            \
    dma16(ahi + ((((size_t)g0_) << 9) + cb_ + c_in * 8),                     \
          &Ah[tb_][(wave * 32) * 32]);                                       \
    dma16(ahi + ((((size_t)g1_) << 9) + cb_ + c_in * 8),                     \
          &Ah[tb_][(wave * 32 + 16) * 32]);                                  \
  }
#define SG_AL(tb_, ks_)                                                      \
  {                                                                          \
    int k0_ = (ks_) * 32, half_ = k0_ >> 9, cb_ = k0_ & 511;                 \
    int g0_ = mrow0 + wave * 32 + r_in + half_;                              \
    int g1_ = g0_ + 16;                                                      \
    if (g0_ > 32767) g0_ = 32767;                                            \
    if (g1_ > 32767) g1_ = 32767;                                            \
    dma16(alo + ((((size_t)g0_) << 9) + cb_ + c_in * 8),                     \
          &Al[tb_][(wave * 32) * 32]);                                       \
    dma16(alo + ((((size_t)g1_) << 9) + cb_ + c_in * 8),                     \
          &Al[tb_][(wave * 32 + 16) * 32]);                                  \
  }
#define SG_BH(tb_, ks_)                                                      \
  {                                                                          \
    int k0_ = (ks_) * 32;                                                    \
    int n0_ = ncol0 + wave * 32 + r_in;                                      \
    dma16(w1h + (((size_t)n0_) << 10) + k0_ + c_in * 8,                      \
          &Bh[tb_][(wave * 32) * 32]);                                       \
    dma16(w1h + (((size_t)(n0_ + 16)) << 10) + k0_ + c_in * 8,               \
          &Bh[tb_][(wave * 32 + 16) * 32]);                                  \
  }
#define SG_BL(tb_, ks_)                                                      \
  {                                                                          \
    int k0_ = (ks_) * 32;                                                    \
    int n0_ = ncol0 + wave * 32 + r_in;                                      \
    dma16(w1l + (((size_t)n0_) << 10) + k0_ + c_in * 8,                      \
          &Bl[tb_][(wave * 32) * 32]);                                       \
    dma16(w1l + (((size_t)(n0_ + 16)) << 10) + k0_ + c_in * 8,               \
          &Bl[tb_][(wave * 32 + 16) * 32]);                                  \
  }

  f32x4 acc[8][4];
#pragma unroll
  for (int mi = 0; mi < 8; ++mi)
#pragma unroll
    for (int ni = 0; ni < 4; ++ni) acc[mi][ni] = (f32x4){0.f, 0.f, 0.f, 0.f};

  // per-lane fragment base byte/element offsets in a plane buffer
  const int a_off0 = (wm * 128 + l15) * 32 + quad * 8;   // + mi*512
  const int b_off0 = (wn * 64 + l15) * 32 + quad * 8;    // + ni*512

  bf16x8 ahA[8], bhA[4], ahB[8], bhB[4];

  // prologue: stage tile 0; drain AH,BH,BL (leave AL in flight); read ah,bh(0)
  SG_AH(0, 0) SG_BH(0, 0) SG_BL(0, 0) SG_AL(0, 0)
  asm volatile("s_waitcnt vmcnt(2)" ::: "memory");
  __builtin_amdgcn_s_barrier();
#pragma unroll
  for (int mi = 0; mi < 8; ++mi) ahA[mi] = *(const bf16x8*)&Ah[0][a_off0 + mi * 512];
#pragma unroll
  for (int ni = 0; ni < 4; ++ni) bhA[ni] = *(const bf16x8*)&Bh[0][b_off0 + ni * 512];

#define STEP(bb_, ks_, AH_IN, BH_IN, AH_OUT, BH_OUT)                         \
  {                                                                          \
    const int nx_ = ((ks_) + 1 < 32) ? ((ks_) + 1) : 31;                     \
    bf16x8 bl_[4], al_[8];                                                   \
    /* ---- ph0: hh; tail: stage AH/BH(next), read bl(ks) */                 \
    asm volatile("s_waitcnt lgkmcnt(0)" ::: "memory");                       \
    __builtin_amdgcn_sched_barrier(0);                                       \
    __builtin_amdgcn_s_setprio(1);                                           \
    _Pragma("unroll")                                                        \
    for (int ni_ = 0; ni_ < 4; ++ni_)                                        \
      _Pragma("unroll")                                                      \
      for (int mi_ = 0; mi_ < 8; ++mi_)                                      \
        acc[mi_][ni_] = __builtin_amdgcn_mfma_f32_16x16x32_bf16(             \
            AH_IN[mi_], BH_IN[ni_], acc[mi_][ni_], 0, 0, 0);                 \
    __builtin_amdgcn_s_setprio(0);                                           \
    SG_AH((bb_) ^ 1, nx_) SG_BH((bb_) ^ 1, nx_)                              \
    _Pragma("unroll")                                                        \
    for (int ni_ = 0; ni_ < 4; ++ni_)                                        \
      bl_[ni_] = *(const bf16x8*)&Bl[bb_][b_off0 + ni_ * 512];               \
    asm volatile("s_waitcnt vmcnt(4)" ::: "memory");                         \
    __builtin_amdgcn_s_barrier();                                            \
    /* ---- ph1: hl; tail: stage BL/AL(next), read al(ks) */                 \
    asm volatile("s_waitcnt lgkmcnt(0)" ::: "memory");                       \
    __builtin_amdgcn_sched_barrier(0);                                       \
    __builtin_amdgcn_s_setprio(1);                                           \
    _Pragma("unroll")                                                        \
    for (int ni_ = 0; ni_ < 4; ++ni_)                                        \
      _Pragma("unroll")                                                      \
      for (int mi_ = 0; mi_ < 8; ++mi_)                                      \
        acc[mi_][ni_] = __builtin_amdgcn_mfma_f32_16x16x32_bf16(             \
            AH_IN[mi_], bl_[ni_], acc[mi_][ni_], 0, 0, 0);                   \
    __builtin_amdgcn_s_setprio(0);                                           \
    SG_BL((bb_) ^ 1, nx_) SG_AL((bb_) ^ 1, nx_)                              \
    _Pragma("unroll")                                                        \
    for (int mi_ = 0; mi_ < 8; ++mi_)                                        \
      al_[mi_] = *(const bf16x8*)&Al[bb_][a_off0 + mi_ * 512];               \
    asm volatile("s_waitcnt vmcnt(4)" ::: "memory");                         \
    __builtin_amdgcn_s_barrier();                                            \
    /* ---- ph2: lh; tail: read ah,bh(next tile) */                          \
    asm volatile("s_waitcnt lgkmcnt(0)" ::: "memory");                       \
    __builtin_amdgcn_sched_barrier(0);                                       \
    __builtin_amdgcn_s_setprio(1);                                           \
    _Pragma("unroll")                                                        \
    for (int ni_ = 0; ni_ < 4; ++ni_)                                        \
      _Pragma("unroll")                                                      \
      for (int mi_ = 0; mi_ < 8; ++mi_)                                      \
        acc[mi_][ni_] = __builtin_amdgcn_mfma_f32_16x16x32_bf16(             \
            al_[mi_], BH_IN[ni_], acc[mi_][ni_], 0, 0, 0);                   \
    __builtin_amdgcn_s_setprio(0);                                           \
    _Pragma("unroll")                                                        \
    for (int mi_ = 0; mi_ < 8; ++mi_)                                        \
      AH_OUT[mi_] = *(const bf16x8*)&Ah[(bb_) ^ 1][a_off0 + mi_ * 512];      \
    _Pragma("unroll")                                                        \
    for (int ni_ = 0; ni_ < 4; ++ni_)                                        \
      BH_OUT[ni_] = *(const bf16x8*)&Bh[(bb_) ^ 1][b_off0 + ni_ * 512];      \
    asm volatile("s_waitcnt vmcnt(2)" ::: "memory");                         \
    __builtin_amdgcn_s_barrier();                                            \
  }

  for (int ks = 0; ks < 32; ks += 2) {
    STEP(0, ks,     ahA, bhA, ahB, bhB)
    STEP(1, ks + 1, ahB, bhB, ahA, bhA)
  }
#undef STEP
#undef SG_AH
#undef SG_AL
#undef SG_BH
#undef SG_BL

  // drain tail dummy dmas (they target Ah[0], reused as `red` below)
  asm volatile("s_waitcnt vmcnt(0)" ::: "memory");
  __syncthreads();

  // epilogue: relu(acc + b1) . W2 over this wave's 64 cols; shfl-reduce over
  // l15, then cross-wave (wn) reduce via LDS (reuse dead Ah staging space).
  float* red = (float*)&Ah[0][0];     // 8 waves * 128 rows * 4 B = 4 KB
  float b1v[4], w2v[4];
#pragma unroll
  for (int ni = 0; ni < 4; ++ni) {
    int n_g = ncol0 + wn * 64 + ni * 16 + l15;
    b1v[ni] = b1[n_g];
    w2v[ni] = W2[n_g];
  }
#pragma unroll
  for (int mi = 0; mi < 8; ++mi) {
#pragma unroll
    for (int reg = 0; reg < 4; ++reg) {
      float part = 0.f;
#pragma unroll
      for (int ni = 0; ni < 4; ++ni) {
        float h = acc[mi][ni][reg] + b1v[ni];
        h = h > 0.f ? h : 0.f;
        part = fmaf(h, w2v[ni], part);
      }
#pragma unroll
      for (int m = 8; m; m >>= 1) part += __shfl_xor(part, m, 64);
      if (l15 == 0) red[wave * 128 + mi * 16 + quad * 4 + reg] = part;
    }
  }
  __syncthreads();
  if (tid < 256) {
    int wmr = tid >> 7, rl = tid & 127;
    float s = red[(wmr * 4 + 0) * 128 + rl] + red[(wmr * 4 + 1) * 128 + rl]
            + red[(wmr * 4 + 2) * 128 + rl] + red[(wmr * 4 + 3) * 128 + rl];
    int grow = mrow0 + tid;
    int b = grow >> 10, n = grow & 1023;
    if (n < NS)
      Spart[((size_t)nblk * BB + b) * NN + n] = s;
  }
}

// ---------------------------------------------------------------- kernel 3
__global__ __launch_bounds__(256) void k_row(const float* __restrict__ S0,
                                             const float* __restrict__ S1,
                                             const float* __restrict__ mask,
                                             int* __restrict__ assign,
                                             float* __restrict__ weight,
                                             float* __restrict__ total,
                                             int* __restrict__ startn,
                                             int* __restrict__ endn) {
  int b = blockIdx.x, tid = threadIdx.x;
  __shared__ float Ssh[NS];
  __shared__ float Dsh[NS];
  __shared__ float tsh[NN];
  __shared__ float bsh[NN];
  __shared__ float totl[NN];
  __shared__ int   stl[NN];
  __shared__ int   enl[NN];
  __shared__ float red[256];

  for (int n = tid; n < NS; n += 256)
    Ssh[n] = S0[((size_t)b << 10) + n] + S1[((size_t)b << 10) + n];
  __syncthreads();

  float mn = INFINITY, mx = -INFINITY;
  for (int n = tid; n < NS; n += 256) {
    float v = Ssh[n];
    mn = fminf(mn, v); mx = fmaxf(mx, v);
  }
  red[tid] = mn; __syncthreads();
  for (int s = 128; s; s >>= 1) { if (tid < s) red[tid] = fminf(red[tid], red[tid + s]); __syncthreads(); }
  float Smin = red[0]; __syncthreads();
  red[tid] = mx; __syncthreads();
  for (int s = 128; s; s >>= 1) { if (tid < s) red[tid] = fmaxf(red[tid], red[tid + s]); __syncthreads(); }
  float Smax = red[0]; __syncthreads();

  for (int n = tid; n < NS; n += 256)
    Dsh[n] = 1.0f - (Ssh[n] - Smin) / (Smax - Smin);
  __syncthreads();

  for (int n = tid; n < NN; n += 256) {
    float P;
    if (n >= NS) {
      P = 0.f;
    } else {
      float D = Dsh[n];
      float fo, so;
      if (n == 0)            fo = fmaxf(D - Dsh[1], 0.f);
      else if (n >= NS - 2)  fo = fmaxf(D - Dsh[n - 2], 0.f);
      else                   fo = fminf(fmaxf(D - Dsh[n - 1], 0.f),
                                        fmaxf(D - Dsh[n + 1], 0.f));
      if (n <= 1)            so = fmaxf(D - Dsh[n + 2], 0.f);
      else if (n >= NS - 2)  so = 0.f;
      else                   so = fminf(fmaxf(D - Dsh[n - 2], 0.f),
                                        fmaxf(D - Dsh[n + 2], 0.f));
      P = fminf(fmaxf(fmaxf(fo, so) - 0.05f, 0.f), fo);
    }
    float m = mask[((size_t)b << 10) + n];
    P = P + (m - 1.0f);
    P = P > 0.f ? P : 0.f;
    float bs = tanhf(10.0f * P);
    float bh = tanhf(100000.0f * P);
    tsh[n] = bs + (bh - bs);
  }
  __syncthreads();

  if (tid == 0) {
    float acc = 0.f;
    for (int n = 0; n < NN; n += 8) {
      float t0 = tsh[n + 0], t1 = tsh[n + 1], t2 = tsh[n + 2], t3 = tsh[n + 3];
      float t4 = tsh[n + 4], t5 = tsh[n + 5], t6 = tsh[n + 6], t7 = tsh[n + 7];
      acc += t0; bsh[n + 0] = acc; acc += t1; bsh[n + 1] = acc;
      acc += t2; bsh[n + 2] = acc; acc += t3; bsh[n + 3] = acc;
      acc += t4; bsh[n + 4] = acc; acc += t5; bsh[n + 5] = acc;
      acc += t6; bsh[n + 6] = acc; acc += t7; bsh[n + 7] = acc;
    }
  }
  __syncthreads();

  float add1 = (bsh[0] == 0.0f) ? 1.0f : 0.0f;
  int   num  = (int)(bsh[NN - 1] + add1) + 1;

  for (int mi = tid; mi < NN; mi += 256) { totl[mi] = 0.f; stl[mi] = 1 << 30; enl[mi] = -1; }
  __syncthreads();

  for (int n = tid; n < NN; n += 256) {
    float bv = bsh[n] + add1;
    float kf = rintf(bv);
    int   k  = (int)kf;
    int   a  = -1; float w = 0.f;
    if (k >= 1 && k <= num && k <= NN) {
      float v = fabsf(kf - bv);
      w = 1.0f - tanhf(100000.0f * v);
      if (w > 0.f) {
        a = k - 1;
        atomicAdd(&totl[a], w);
        atomicMin(&stl[a], n);
        atomicMax(&enl[a], n);
      } else {
        a = -1; w = 0.f;
      }
    }
    assign[((size_t)b << 10) + n] = a;
    weight[((size_t)b << 10) + n] = w;
  }
  __syncthreads();
  for (int mi = tid; mi < NN; mi += 256) {
    total [((size_t)b << 10) + mi] = totl[mi];
    startn[((size_t)b << 10) + mi] = stl[mi];
    endn  [((size_t)b << 10) + mi] = enl[mi];
  }
}

// ---------------------------------------------------------------- kernel 4
// pool -> wrep bf16 into first half of each d_out row region + zero-mask
// byte per 8 cols into mb (reuses dead w1h region).
__global__ __launch_bounds__(64) void k_pool(const float* __restrict__ seg,
                                             const int* __restrict__ assign,
                                             const float* __restrict__ weight,
                                             const float* __restrict__ total,
                                             const int* __restrict__ startn,
                                             const int* __restrict__ endn,
                                             u16* hrep,
                                             unsigned char* __restrict__ mb) {
  int bm = blockIdx.x;
  int b  = bm >> 10, m = bm & 1023;
  int lane = threadIdx.x;
  float acc[8] = {0.f, 0.f, 0.f, 0.f, 0.f, 0.f, 0.f, 0.f};
  float tm = total[bm];
  if (tm > 0.f) {
    int s = startn[bm], e = endn[bm];
    for (int n = s; n <= e; ++n) {
      if (assign[((size_t)b << 10) + n] != m) continue;
      float coef = weight[((size_t)b << 10) + n] / tm;
      const float4* p = (const float4*)(seg + (((size_t)b << 10) + n) * HH + lane * 8);
      float4 x = p[0], y = p[1];
      acc[0] = fmaf(coef, x.x, acc[0]); acc[1] = fmaf(coef, x.y, acc[1]);
      acc[2] = fmaf(coef, x.z, acc[2]); acc[3] = fmaf(coef, x.w, acc[3]);
      acc[4] = fmaf(coef, y.x, acc[4]); acc[5] = fmaf(coef, y.y, acc[5]);
      acc[6] = fmaf(coef, y.z, acc[6]); acc[7] = fmaf(coef, y.w, acc[7]);
    }
  }
  u16 h[8];
  unsigned int mbyte = 0;
#pragma unroll
  for (int j = 0; j < 8; ++j) {
    h[j] = f2bf(acc[j]);
    mbyte |= (acc[j] == 0.f ? 1u : 0u) << j;
  }
  *(uint4*)(hrep + ((size_t)bm << 10) + lane * 8) =
      make_uint4(h[0] | (h[1] << 16), h[2] | (h[3] << 16),
                 h[4] | (h[5] << 16), h[6] | (h[7] << 16));
  mb[((size_t)bm << 6) + lane] = (unsigned char)mbyte;
}

// ---------------------------------------------------------------- out-MLP GEMMs
// mode 1: Hid = relu(wrep_bf16 @ We1 + be1) -> bf16 at row*1024 + 512 + n
// mode 2: out = (Hid @ We2 + be2) masked    -> fp32 full row
// round-2 structure (76 KB LDS, mixed depth-2 A-ring) — measured best.
__global__ __launch_bounds__(512, 4) void k_g(const u16* asrc,
                                              const u16* __restrict__ bmat,
                                              const float* __restrict__ bias,
                                              const unsigned char* __restrict__ mb,
                                              float* outp,
                                              u16* hid,
                                              int a_off, int mode) {
  __shared__ u16 As[3][64 * 32];    // 12 KB (3-slot ring)
  __shared__ u16 Bs[2][512 * 32];   // 64 KB

  const int tid  = threadIdx.x;
  const int wave = tid >> 6, lane = tid & 63;
  const int quad = lane >> 4, l15 = lane & 15;
  const int wm = wave >> 2, wn = wave & 3;
  const int r_in = lane >> 2, c_in = lane & 3;
  const int mrow0 = blockIdx.x * 64;

#define SGB(tb_, ks_)                                                        \
  {                                                                          \
    int k0_ = (ks_) * 32;                                                    \
    _Pragma("unroll")                                                        \
    for (int g_ = 0; g_ < 4; ++g_) {                                         \
      int n_ = wave * 64 + g_ * 16 + r_in;                                   \
      dma16(bmat + (size_t)n_ * 512 + k0_ + c_in * 8,                        \
            &Bs[tb_][(wave * 64 + g_ * 16) * 32]);                           \
    }                                                                        \
  }
#define SGA(sl_, ks_)                                                        \
  {                                                                          \
    if (wave < 4) {                                                          \
      int k0_ = (ks_) * 32;                                                  \
      int row_ = wave * 16 + r_in;                                           \
      dma16(asrc + ((size_t)(mrow0 + row_) << 10) + a_off + k0_ + c_in * 8,  \
            &As[sl_][(wave * 16) * 32]);                                     \
    }                                                                        \
  }

  f32x4 acc[2][8];
#pragma unroll
  for (int mi = 0; mi < 2; ++mi)
#pragma unroll
    for (int ni = 0; ni < 8; ++ni) acc[mi][ni] = (f32x4){0.f, 0.f, 0.f, 0.f};

  // prologue: B(0) then A(0) then A(1); drain B(0),A(0); A(1) stays in flight
  SGB(0, 0) SGA(0, 0) SGA(1, 1)
  if (wave < 4) { asm volatile("s_waitcnt vmcnt(1)" ::: "memory"); }
  else          { asm volatile("s_waitcnt vmcnt(0)" ::: "memory"); }
  __builtin_amdgcn_s_barrier();
  // invariant at step entry: outstanding(wave<4) = {A(ks+1)}, (wave>=4) = {}

  for (int ks = 0; ks < 16; ++ks) {
    const int bb = ks & 1;
    const int ra = ks % 3;
    const int nb = (ks + 1 < 16) ? ks + 1 : 15;   // tail: dummy restage
    const int na = (ks + 2 < 16) ? ks + 2 : 15;
    SGB(bb ^ 1, nb)              // +4 (issued oldest-first after A(ks+1))
    SGA((ks + 2) % 3, na)        // +1 for waves 0-3
    bf16x8 a[2], b[8];
#pragma unroll
    for (int mi = 0; mi < 2; ++mi)
      a[mi] = *(const bf16x8*)&As[ra][(wm * 32 + mi * 16 + l15) * 32 + quad * 8];
#pragma unroll
    for (int ni = 0; ni < 8; ++ni)
      b[ni] = *(const bf16x8*)&Bs[bb][(wn * 128 + ni * 16 + l15) * 32 + quad * 8];
    asm volatile("s_waitcnt lgkmcnt(0)" ::: "memory");
    __builtin_amdgcn_sched_barrier(0);
    __builtin_amdgcn_s_setprio(1);
#pragma unroll
    for (int ni = 0; ni < 8; ++ni)
#pragma unroll
      for (int mi = 0; mi < 2; ++mi)
        acc[mi][ni] = __builtin_amdgcn_mfma_f32_16x16x32_bf16(a[mi], b[ni], acc[mi][ni], 0, 0, 0);
    __builtin_amdgcn_s_setprio(0);
    // drain A(ks+1) + B(ks+1); leave A(ks+2) in flight
    if (wave < 4) { asm volatile("s_waitcnt vmcnt(1)" ::: "memory"); }
    else          { asm volatile("s_waitcnt vmcnt(0)" ::: "memory"); }
    __builtin_amdgcn_s_barrier();
  }
#undef SGB
#undef SGA
  // drain the tail dummy so no in-flight LDS write can outlive this block
  asm volatile("s_waitcnt vmcnt(0)" ::: "memory");

  float bv[8];
#pragma unroll
  for (int ni = 0; ni < 8; ++ni) bv[ni] = bias[wn * 128 + ni * 16 + l15];

  if (mode == 1) {
    // Hid = relu(acc + be1) -> bf16 second half of own row regions
#pragma unroll
    for (int mi = 0; mi < 2; ++mi)
#pragma unroll
      for (int ni = 0; ni < 8; ++ni)
#pragma unroll
        for (int reg = 0; reg < 4; ++reg) {
          int col = wn * 128 + ni * 16 + l15;
          int row = mrow0 + wm * 32 + mi * 16 + quad * 4 + reg;
          float h = acc[mi][ni][reg] + bv[ni];
          h = h > 0.f ? h : 0.f;
          hid[((size_t)row << 10) + 512 + col] = f2bf(h);
        }
  } else {
    // out = (acc + be2) with (wrep==0) mask -> fp32 full row, in place
#pragma unroll
    for (int mi = 0; mi < 2; ++mi)
#pragma unroll
      for (int ni = 0; ni < 8; ++ni)
#pragma unroll
        for (int reg = 0; reg < 4; ++reg) {
          int col = wn * 128 + ni * 16 + l15;
          int row = mrow0 + wm * 32 + mi * 16 + quad * 4 + reg;
          float o = acc[mi][ni][reg] + bv[ni];
          unsigned char m8 = mb[((size_t)row << 6) + (col >> 3)];
          outp[((size_t)row << 9) + col] = ((m8 >> (col & 7)) & 1) ? 0.f : o;
        }
  }
}

// ---------------------------------------------------------------- diag (hostcode only)
__global__ void k_diag(float* __restrict__ out, int hostcode) {
  if (hostcode != 0) out[0] = (float)hostcode;
}

// ---------------------------------------------------------------- launch
extern "C" void kernel_launch(void* const* d_in, const int* in_sizes, int n_in,
                              void* d_out, int out_size, void* d_ws, size_t ws_size,
                              hipStream_t stream) {
  const float* seg  = (const float*)d_in[0];
  const float* mask = (const float*)d_in[1];
  const float* W1   = (const float*)d_in[2];
  const float* b1   = (const float*)d_in[3];
  const float* W2   = (const float*)d_in[4];
  const float* We1  = (const float*)d_in[5];
  const float* be1  = (const float*)d_in[6];
  const float* We2  = (const float*)d_in[7];
  const float* be2  = (const float*)d_in[8];

  const size_t NROW = (size_t)BB * NN;            // 32768
  float* ws = (float*)d_ws;
  float* S0     = ws;                             // partial S, nblk=0
  float* S1     = S0 + NROW;                      // partial S, nblk=1
  int*   assign = (int*)(S1 + NROW);
  float* weight = (float*)(assign + NROW);
  float* total  = weight + NROW;
  int*   startn = (int*)(total + NROW);
  int*   endn   = startn + NROW;
  u16*   w1h    = (u16*)(endn + NROW);            // [n=512][k=1024]
  u16*   w1l    = w1h + (size_t)512 * 1024;
  u16*   we1t   = w1l + (size_t)512 * 1024;       // [n=512][k=512]
  u16*   we2t   = we1t + (size_t)512 * 512;       // end ~4.8 MB

  float* out = (float*)d_out;
  u16*   ahi = (u16*)d_out;                       // A hi plane (33.5 MB)
  u16*   alo = ahi + (size_t)NROW * HH;           // A lo plane (33.5 MB)
  u16*   hrep = (u16*)d_out;                      // wrep bf16 + Hid bf16 rows
  unsigned char* mbuf = (unsigned char*)w1h;      // 2 MB mask (w1h+w1l dead)

  int hostcode = 0;
  if (ws_size < (size_t)7 * NROW * 4 + (size_t)3 * 1024 * 1024) hostcode += 32768;
  if (out_size != 16777216) hostcode += 8192;

  k_prep_a<<<dim3(BB * NN / 4), dim3(256), 0, stream>>>(seg, ahi, alo);
  k_tr3   <<<dim3(8, 16, 3), dim3(256), 0, stream>>>(W1, We1, We2, w1h, w1l, we1t, we2t);
  k_sgemm <<<dim3(256), dim3(512), 0, stream>>>(ahi, alo, w1h, w1l, b1, W2, S0);
  k_row   <<<dim3(BB), dim3(256), 0, stream>>>(S0, S1, mask, assign, weight, total, startn, endn);
  k_pool  <<<dim3(BB * NN), dim3(64), 0, stream>>>(seg, assign, weight, total, startn, endn, hrep, mbuf);
  k_g     <<<dim3(512), dim3(512), 0, stream>>>(hrep, we1t, be1, mbuf, out, hrep, 0,   1);
  k_g     <<<dim3(512), dim3(512), 0, stream>>>(hrep, we2t, be2, mbuf, out, hrep, 512, 2);
  k_diag  <<<dim3(1), dim3(1), 0, stream>>>(out, hostcode);
}

// Round 8
// 314.058 us; speedup vs baseline: 1.0187x; 1.0187x over previous
//
#include <hip/hip_runtime.h>

#define BB 32
#define NN 1024
#define HH 512
#define NS 1023   // S length per row

typedef unsigned short u16;
typedef unsigned int   u32;
typedef __attribute__((ext_vector_type(8))) short bf16x8;
typedef __attribute__((ext_vector_type(4))) float f32x4;

__device__ __forceinline__ float bf2f(u16 h) {
  union { u32 u; float f; } c; c.u = ((u32)h) << 16; return c.f;
}
__device__ __forceinline__ u16 f2bf(float f) {
  union { float f; u32 u; } c; c.f = f;
  u32 u = c.u;
  return (u16)((u + 0x7fffu + ((u >> 16) & 1u)) >> 16);
}
// split x = hi + lo (each bf16); residual ~2^-18 relative
__device__ __forceinline__ void split_bf(float x, u16& hi, u16& lo) {
  hi = f2bf(x);
  lo = f2bf(x - bf2f(hi));
}
// async global->LDS DMA, 16 B per lane; LDS dest = wave-uniform base + lane*16
__device__ __forceinline__ void dma16(const u16* g, u16* l) {
  __builtin_amdgcn_global_load_lds(
      (const __attribute__((address_space(1))) u32*)g,
      (__attribute__((address_space(3))) u32*)l, 16, 0, 0);
}

// ---------------------------------------------------------------- prep A
// 256 threads = 4 waves, one row per wave
__global__ __launch_bounds__(256) void k_prep_a(const float* __restrict__ seg,
                                                u16* __restrict__ ahi,
                                                u16* __restrict__ alo) {
  int row = blockIdx.x * 4 + (threadIdx.x >> 6);
  int lane = threadIdx.x & 63;
  const float4* p = (const float4*)(seg + ((size_t)row << 9) + lane * 8);
  float4 a = p[0], b = p[1];
  float v[8] = {a.x, a.y, a.z, a.w, b.x, b.y, b.z, b.w};
  float s = 0.f;
#pragma unroll
  for (int i = 0; i < 8; ++i) s += v[i] * v[i];
#pragma unroll
  for (int m = 32; m; m >>= 1) s += __shfl_xor(s, m, 64);
  float nrm = sqrtf(s);
  u16 h[8], l[8];
#pragma unroll
  for (int i = 0; i < 8; ++i) split_bf(v[i] / nrm, h[i], l[i]);
  size_t off = ((size_t)row << 9) + lane * 8;
  *(uint4*)(ahi + off) = make_uint4(h[0] | (h[1] << 16), h[2] | (h[3] << 16),
                                    h[4] | (h[5] << 16), h[6] | (h[7] << 16));
  *(uint4*)(alo + off) = make_uint4(l[0] | (l[1] << 16), l[2] | (l[3] << 16),
                                    l[4] | (l[5] << 16), l[6] | (l[7] << 16));
}

// ---------------------------------------------------------------- transpose-split
// merged: z=0 -> W1 (K=1024), z=1 -> We1, z=2 -> We2 (K=512, y<8 only)
__global__ __launch_bounds__(256) void k_tr3(const float* __restrict__ W1,
                                             const float* __restrict__ We1,
                                             const float* __restrict__ We2,
                                             u16* __restrict__ w1h,
                                             u16* __restrict__ w1l,
                                             u16* __restrict__ we1t,
                                             u16* __restrict__ we2t) {
  __shared__ u16 Th[64 * 66], Tl[64 * 66];
  int z = blockIdx.z;
  const float* src; u16 *dh, *dl; int K, N;
  if (z == 0)      { src = W1;  dh = w1h;  dl = w1l;          K = 1024; N = 512; }
  else if (z == 1) { src = We1; dh = we1t; dl = (u16*)0;      K = 512;  N = 512; }
  else             { src = We2; dh = we2t; dl = (u16*)0;      K = 512;  N = 512; }
  if (blockIdx.y * 64 >= K) return;   // uniform per block, before any barrier
  int nb = blockIdx.x * 64, kb = blockIdx.y * 64;
  int tid = threadIdx.x;
#pragma unroll
  for (int i = 0; i < 16; ++i) {
    int e = tid + i * 256;
    int r = e >> 6, c = e & 63;
    float v = src[(size_t)(kb + r) * N + nb + c];
    u16 hi, lo; split_bf(v, hi, lo);
    Th[c * 66 + r] = hi;
    Tl[c * 66 + r] = lo;
  }
  __syncthreads();
#pragma unroll
  for (int i = 0; i < 16; ++i) {
    int e = tid + i * 256;
    int n = e >> 6, k = e & 63;
    dh[(size_t)(nb + n) * K + kb + k] = Th[n * 66 + k];
    if (dl) dl[(size_t)(nb + n) * K + kb + k] = Tl[n * 66 + k];
  }
}

// ---------------------------------------------------------------- S-GEMM (MFMA)
// RESTORED round-3 version verbatim (measured 86.1-86.6 us, MfmaUtil ~51%).
// 256m x 256n block, BK=32, 8 waves (2m x 4n), wave tile 128x64.
// XCD-twin remap: 1-D grid 256, xcd = w&7, slot = w>>3; nblk = slot&1,
// mblk = xcd*16 + (slot>>1) -> nblk twins of each mblk share an XCD L2 ->
// A fetched ~once from HBM (FETCH 73.8 MB verified).
// 3 phases/K-step (hh, hl, lh), plane-split staging, counted vmcnt (6/8/4),
// never 0 in the main loop. Schedule alternatives measured WORSE:
// single-barrier 98.5 us (r5), reads-trail-MFMA 96.4 us (r7) — keep this.
// Per-accumulator addend order (hh, hl, lh) -> bit-exact numerics.
__global__ __launch_bounds__(512, 2) void k_sgemm(const u16* __restrict__ ahi,
                                                  const u16* __restrict__ alo,
                                                  const u16* __restrict__ w1h,
                                                  const u16* __restrict__ w1l,
                                                  const float* __restrict__ b1,
                                                  const float* __restrict__ W2,
                                                  float* __restrict__ Spart) {
  __shared__ u16 Ah[2][256 * 32];   // 32 KB
  __shared__ u16 Al[2][256 * 32];   // 32 KB
  __shared__ u16 Bh[2][256 * 32];   // 32 KB
  __shared__ u16 Bl[2][256 * 32];   // 32 KB   (total 128 KiB)

  const int tid  = threadIdx.x;
  const int wave = tid >> 6, lane = tid & 63;
  const int quad = lane >> 4, l15 = lane & 15;
  const int wm = wave >> 2, wn = wave & 3;
  const int r_in = lane >> 2, c_in = lane & 3;   // DMA chunk coords
  const int w    = blockIdx.x;                   // 0..255
  const int xcd  = w & 7, slot = w >> 3;
  const int nblk = slot & 1;
  const int mblk = xcd * 16 + (slot >> 1);
  const int mrow0 = mblk * 256;
  const int ncol0 = nblk * 256;

  // plane-split staging: each macro = 2 dma16/wave, covers this wave's 32 rows
#define SG_AH(tb_, ks_)                                                      \
  {                                                                          \
    int k0_ = (ks_) * 32, half_ = k0_ >> 9, cb_ = k0_ & 511;                 \
    int g0_ = mrow0 + wave * 32 + r_in + half_;                              \
    int g1_ = g0_ + 16;                                                      \
    if (g0_ > 32767) g0_ = 32767;                                            \
    if (g1_ > 32767) g1_ = 32767;                                            \
    dma16(ahi + ((((size_t)g0_) << 9) + cb_ + c_in * 8),                     \
          &Ah[tb_][(wave * 32) * 32]);                                       \
    dma16(ahi + ((((size_t)g1_) << 9) + cb_ + c_in * 8),                     \
          &Ah[tb_][(wave * 32 + 16) * 32]);                                  \
  }
#define SG_AL(tb_, ks_)                                                      \
  {                                                                          \
    int k0_ = (ks_) * 32, half_ = k0_ >> 9, cb_ = k0_ & 511;                 \
    int g0_ = mrow0 + wave * 32 + r_in + half_;                              \
    int g1_ = g0_ + 16;                                                      \
    if (g0_ > 32767) g0_ = 32767;                                            \
    if (g1_ > 32767) g1_ = 32767;                                            \
    dma16(alo + ((((size_t)g0_) << 9) + cb_ + c_in * 8),                     \
          &Al[tb_][(wave * 32) * 32]);                                       \
    dma16(alo + ((((size_t)g1_) << 9) + cb_ + c_in * 8),                     \
          &Al[tb_][(wave * 32 + 16) * 32]);                                  \
  }
#define SG_BH(tb_, ks_)                                                      \
  {                                                                          \
    int k0_ = (ks_) * 32;                                                    \
    int n0_ = ncol0 + wave * 32 + r_in;                                      \
    dma16(w1h + (((size_t)n0_) << 10) + k0_ + c_in * 8,                      \
          &Bh[tb_][(wave * 32) * 32]);                                       \
    dma16(w1h + (((size_t)(n0_ + 16)) << 10) + k0_ + c_in * 8,               \
          &Bh[tb_][(wave * 32 + 16) * 32]);                                  \
  }
#define SG_BL(tb_, ks_)                                                      \
  {                                                                          \
    int k0_ = (ks_) * 32;                                                    \
    int n0_ = ncol0 + wave * 32 + r_in;                                      \
    dma16(w1l + (((size_t)n0_) << 10) + k0_ + c_in * 8,                      \
          &Bl[tb_][(wave * 32) * 32]);                                       \
    dma16(w1l + (((size_t)(n0_ + 16)) << 10) + k0_ + c_in * 8,               \
          &Bl[tb_][(wave * 32 + 16) * 32]);                                  \
  }

  f32x4 acc[8][4];
#pragma unroll
  for (int mi = 0; mi < 8; ++mi)
#pragma unroll
    for (int ni = 0; ni < 4; ++ni) acc[mi][ni] = (f32x4){0.f, 0.f, 0.f, 0.f};

  // prologue: tile 0 in issue order AH,BH (drained now) then BL,AL (in flight)
  SG_AH(0, 0) SG_BH(0, 0) SG_BL(0, 0) SG_AL(0, 0)
  asm volatile("s_waitcnt vmcnt(4)" ::: "memory");
  __builtin_amdgcn_s_barrier();
  // loop invariant at phase-0 entry: outstanding = {BL(ks), AL(ks)} = 4

  for (int ks = 0; ks < 32; ++ks) {
    const int bb = ks & 1;
    const int nx = (ks + 1 < 32) ? ks + 1 : 31;   // last iter: dummy restage
    bf16x8 ah[8], al[8], bh[4], bl[4];

    // ---- phase 0: hi*hi. Reads Ah/Bh[bb] (drained at prev step end).
#pragma unroll
    for (int mi = 0; mi < 8; ++mi)
      ah[mi] = *(const bf16x8*)&Ah[bb][(wm * 128 + mi * 16 + l15) * 32 + quad * 8];
#pragma unroll
    for (int ni = 0; ni < 4; ++ni)
      bh[ni] = *(const bf16x8*)&Bh[bb][(wn * 64 + ni * 16 + l15) * 32 + quad * 8];
    SG_AH(bb ^ 1, nx) SG_BH(bb ^ 1, nx)          // outstanding: 4 -> 8
    asm volatile("s_waitcnt lgkmcnt(0)" ::: "memory");
    __builtin_amdgcn_sched_barrier(0);
    __builtin_amdgcn_s_setprio(1);
#pragma unroll
    for (int ni = 0; ni < 4; ++ni)
#pragma unroll
      for (int mi = 0; mi < 8; ++mi)
        acc[mi][ni] = __builtin_amdgcn_mfma_f32_16x16x32_bf16(ah[mi], bh[ni], acc[mi][ni], 0, 0, 0);
    __builtin_amdgcn_s_setprio(0);
    asm volatile("s_waitcnt vmcnt(6)" ::: "memory");   // drain BL(ks)
    __builtin_amdgcn_s_barrier();

    // ---- phase 1: hi*lo. Reads Bl[bb] (just drained by all waves).
#pragma unroll
    for (int ni = 0; ni < 4; ++ni)
      bl[ni] = *(const bf16x8*)&Bl[bb][(wn * 64 + ni * 16 + l15) * 32 + quad * 8];
    SG_BL(bb ^ 1, nx) SG_AL(bb ^ 1, nx)          // outstanding: <=6 -> <=10
    asm volatile("s_waitcnt lgkmcnt(0)" ::: "memory");
    __builtin_amdgcn_sched_barrier(0);
    __builtin_amdgcn_s_setprio(1);
#pragma unroll
    for (int ni = 0; ni < 4; ++ni)
#pragma unroll
      for (int mi = 0; mi < 8; ++mi)
        acc[mi][ni] = __builtin_amdgcn_mfma_f32_16x16x32_bf16(ah[mi], bl[ni], acc[mi][ni], 0, 0, 0);
    __builtin_amdgcn_s_setprio(0);
    asm volatile("s_waitcnt vmcnt(8)" ::: "memory");   // drain AL(ks)
    __builtin_amdgcn_s_barrier();

    // ---- phase 2: lo*hi. Reads Al[bb] (just drained by all waves).
#pragma unroll
    for (int mi = 0; mi < 8; ++mi)
      al[mi] = *(const bf16x8*)&Al[bb][(wm * 128 + mi * 16 + l15) * 32 + quad * 8];
    asm volatile("s_waitcnt lgkmcnt(0)" ::: "memory");
    __builtin_amdgcn_sched_barrier(0);
    __builtin_amdgcn_s_setprio(1);
#pragma unroll
    for (int ni = 0; ni < 4; ++ni)
#pragma unroll
      for (int mi = 0; mi < 8; ++mi)
        acc[mi][ni] = __builtin_amdgcn_mfma_f32_16x16x32_bf16(al[mi], bh[ni], acc[mi][ni], 0, 0, 0);
    __builtin_amdgcn_s_setprio(0);
    asm volatile("s_waitcnt vmcnt(4)" ::: "memory");   // drain AH,BH(ks+1)
    __builtin_amdgcn_s_barrier();
    // invariant restored: outstanding = {BL(ks+1), AL(ks+1)} = 4
  }
#undef SG_AH
#undef SG_AL
#undef SG_BH
#undef SG_BL

  // drain dummy dmas (they target Ah[0]/... which is reused as `red` below),
  // then barrier so no in-flight write can land after red is written.
  asm volatile("s_waitcnt vmcnt(0)" ::: "memory");
  __syncthreads();

  // epilogue: relu(acc + b1) . W2 over this wave's 64 cols; shfl-reduce over
  // l15, then cross-wave (wn) reduce via LDS (reuse dead Ah staging space).
  float* red = (float*)&Ah[0][0];     // 8 waves * 128 rows * 4 B = 4 KB
  float b1v[4], w2v[4];
#pragma unroll
  for (int ni = 0; ni < 4; ++ni) {
    int n_g = ncol0 + wn * 64 + ni * 16 + l15;
    b1v[ni] = b1[n_g];
    w2v[ni] = W2[n_g];
  }
#pragma unroll
  for (int mi = 0; mi < 8; ++mi) {
#pragma unroll
    for (int reg = 0; reg < 4; ++reg) {
      float part = 0.f;
#pragma unroll
      for (int ni = 0; ni < 4; ++ni) {
        float h = acc[mi][ni][reg] + b1v[ni];
        h = h > 0.f ? h : 0.f;
        part = fmaf(h, w2v[ni], part);
      }
#pragma unroll
      for (int m = 8; m; m >>= 1) part += __shfl_xor(part, m, 64);
      if (l15 == 0) red[wave * 128 + mi * 16 + quad * 4 + reg] = part;
    }
  }
  __syncthreads();
  if (tid < 256) {
    int wmr = tid >> 7, rl = tid & 127;
    float s = red[(wmr * 4 + 0) * 128 + rl] + red[(wmr * 4 + 1) * 128 + rl]
            + red[(wmr * 4 + 2) * 128 + rl] + red[(wmr * 4 + 3) * 128 + rl];
    int grow = mrow0 + tid;
    int b = grow >> 10, n = grow & 1023;
    if (n < NS)
      Spart[((size_t)nblk * BB + b) * NN + n] = s;
  }
}

// ---------------------------------------------------------------- kernel 3
__global__ __launch_bounds__(256) void k_row(const float* __restrict__ S0,
                                             const float* __restrict__ S1,
                                             const float* __restrict__ mask,
                                             int* __restrict__ assign,
                                             float* __restrict__ weight,
                                             float* __restrict__ total,
                                             int* __restrict__ startn,
                                             int* __restrict__ endn) {
  int b = blockIdx.x, tid = threadIdx.x;
  __shared__ float Ssh[NS];
  __shared__ float Dsh[NS];
  __shared__ float tsh[NN];
  __shared__ float bsh[NN];
  __shared__ float totl[NN];
  __shared__ int   stl[NN];
  __shared__ int   enl[NN];
  __shared__ float red[256];

  for (int n = tid; n < NS; n += 256)
    Ssh[n] = S0[((size_t)b << 10) + n] + S1[((size_t)b << 10) + n];
  __syncthreads();

  float mn = INFINITY, mx = -INFINITY;
  for (int n = tid; n < NS; n += 256) {
    float v = Ssh[n];
    mn = fminf(mn, v); mx = fmaxf(mx, v);
  }
  red[tid] = mn; __syncthreads();
  for (int s = 128; s; s >>= 1) { if (tid < s) red[tid] = fminf(red[tid], red[tid + s]); __syncthreads(); }
  float Smin = red[0]; __syncthreads();
  red[tid] = mx; __syncthreads();
  for (int s = 128; s; s >>= 1) { if (tid < s) red[tid] = fmaxf(red[tid], red[tid + s]); __syncthreads(); }
  float Smax = red[0]; __syncthreads();

  for (int n = tid; n < NS; n += 256)
    Dsh[n] = 1.0f - (Ssh[n] - Smin) / (Smax - Smin);
  __syncthreads();

  for (int n = tid; n < NN; n += 256) {
    float P;
    if (n >= NS) {
      P = 0.f;
    } else {
      float D = Dsh[n];
      float fo, so;
      if (n == 0)            fo = fmaxf(D - Dsh[1], 0.f);
      else if (n >= NS - 2)  fo = fmaxf(D - Dsh[n - 2], 0.f);
      else                   fo = fminf(fmaxf(D - Dsh[n - 1], 0.f),
                                        fmaxf(D - Dsh[n + 1], 0.f));
      if (n <= 1)            so = fmaxf(D - Dsh[n + 2], 0.f);
      else if (n >= NS - 2)  so = 0.f;
      else                   so = fminf(fmaxf(D - Dsh[n - 2], 0.f),
                                        fmaxf(D - Dsh[n + 2], 0.f));
      P = fminf(fmaxf(fmaxf(fo, so) - 0.05f, 0.f), fo);
    }
    float m = mask[((size_t)b << 10) + n];
    P = P + (m - 1.0f);
    P = P > 0.f ? P : 0.f;
    float bs = tanhf(10.0f * P);
    float bh = tanhf(100000.0f * P);
    tsh[n] = bs + (bh - bs);
  }
  __syncthreads();

  if (tid == 0) {
    float acc = 0.f;
    for (int n = 0; n < NN; n += 8) {
      float t0 = tsh[n + 0], t1 = tsh[n + 1], t2 = tsh[n + 2], t3 = tsh[n + 3];
      float t4 = tsh[n + 4], t5 = tsh[n + 5], t6 = tsh[n + 6], t7 = tsh[n + 7];
      acc += t0; bsh[n + 0] = acc; acc += t1; bsh[n + 1] = acc;
      acc += t2; bsh[n + 2] = acc; acc += t3; bsh[n + 3] = acc;
      acc += t4; bsh[n + 4] = acc; acc += t5; bsh[n + 5] = acc;
      acc += t6; bsh[n + 6] = acc; acc += t7; bsh[n + 7] = acc;
    }
  }
  __syncthreads();

  float add1 = (bsh[0] == 0.0f) ? 1.0f : 0.0f;
  int   num  = (int)(bsh[NN - 1] + add1) + 1;

  for (int mi = tid; mi < NN; mi += 256) { totl[mi] = 0.f; stl[mi] = 1 << 30; enl[mi] = -1; }
  __syncthreads();

  for (int n = tid; n < NN; n += 256) {
    float bv = bsh[n] + add1;
    float kf = rintf(bv);
    int   k  = (int)kf;
    int   a  = -1; float w = 0.f;
    if (k >= 1 && k <= num && k <= NN) {
      float v = fabsf(kf - bv);
      w = 1.0f - tanhf(100000.0f * v);
      if (w > 0.f) {
        a = k - 1;
        atomicAdd(&totl[a], w);
        atomicMin(&stl[a], n);
        atomicMax(&enl[a], n);
      } else {
        a = -1; w = 0.f;
      }
    }
    assign[((size_t)b << 10) + n] = a;
    weight[((size_t)b << 10) + n] = w;
  }
  __syncthreads();
  for (int mi = tid; mi < NN; mi += 256) {
    total [((size_t)b << 10) + mi] = totl[mi];
    startn[((size_t)b << 10) + mi] = stl[mi];
    endn  [((size_t)b << 10) + mi] = enl[mi];
  }
}

// ---------------------------------------------------------------- kernel 4
// pool -> wrep bf16 into first half of each d_out row region + zero-mask
// byte per 8 cols into mb (reuses dead w1h region).
__global__ __launch_bounds__(64) void k_pool(const float* __restrict__ seg,
                                             const int* __restrict__ assign,
                                             const float* __restrict__ weight,
                                             const float* __restrict__ total,
                                             const int* __restrict__ startn,
                                             const int* __restrict__ endn,
                                             u16* hrep,
                                             unsigned char* __restrict__ mb) {
  int bm = blockIdx.x;
  int b  = bm >> 10, m = bm & 1023;
  int lane = threadIdx.x;
  float acc[8] = {0.f, 0.f, 0.f, 0.f, 0.f, 0.f, 0.f, 0.f};
  float tm = total[bm];
  if (tm > 0.f) {
    int s = startn[bm], e = endn[bm];
    for (int n = s; n <= e; ++n) {
      if (assign[((size_t)b << 10) + n] != m) continue;
      float coef = weight[((size_t)b << 10) + n] / tm;
      const float4* p = (const float4*)(seg + (((size_t)b << 10) + n) * HH + lane * 8);
      float4 x = p[0], y = p[1];
      acc[0] = fmaf(coef, x.x, acc[0]); acc[1] = fmaf(coef, x.y, acc[1]);
      acc[2] = fmaf(coef, x.z, acc[2]); acc[3] = fmaf(coef, x.w, acc[3]);
      acc[4] = fmaf(coef, y.x, acc[4]); acc[5] = fmaf(coef, y.y, acc[5]);
      acc[6] = fmaf(coef, y.z, acc[6]); acc[7] = fmaf(coef, y.w, acc[7]);
    }
  }
  u16 h[8];
  unsigned int mbyte = 0;
#pragma unroll
  for (int j = 0; j < 8; ++j) {
    h[j] = f2bf(acc[j]);
    mbyte |= (acc[j] == 0.f ? 1u : 0u) << j;
  }
  *(uint4*)(hrep + ((size_t)bm << 10) + lane * 8) =
      make_uint4(h[0] | (h[1] << 16), h[2] | (h[3] << 16),
                 h[4] | (h[5] << 16), h[6] | (h[7] << 16));
  mb[((size_t)bm << 6) + lane] = (unsigned char)mbyte;
}

// ---------------------------------------------------------------- out-MLP GEMMs
// mode 1: Hid = relu(wrep_bf16 @ We1 + be1) -> bf16 at row*1024 + 512 + n
// mode 2: out = (Hid @ We2 + be2) masked    -> fp32 full row
// round-2 structure (76 KB LDS, mixed depth-2 A-ring) — measured best.
__global__ __launch_bounds__(512, 4) void k_g(const u16* asrc,
                                              const u16* __restrict__ bmat,
                                              const float* __restrict__ bias,
                                              const unsigned char* __restrict__ mb,
                                              float* outp,
                                              u16* hid,
                                              int a_off, int mode) {
  __shared__ u16 As[3][64 * 32];    // 12 KB (3-slot ring)
  __shared__ u16 Bs[2][512 * 32];   // 64 KB

  const int tid  = threadIdx.x;
  const int wave = tid >> 6, lane = tid & 63;
  const int quad = lane >> 4, l15 = lane & 15;
  const int wm = wave >> 2, wn = wave & 3;
  const int r_in = lane >> 2, c_in = lane & 3;
  const int mrow0 = blockIdx.x * 64;

#define SGB(tb_, ks_)                                                        \
  {                                                                          \
    int k0_ = (ks_) * 32;                                                    \
    _Pragma("unroll")                                                        \
    for (int g_ = 0; g_ < 4; ++g_) {                                         \
      int n_ = wave * 64 + g_ * 16 + r_in;                                   \
      dma16(bmat + (size_t)n_ * 512 + k0_ + c_in * 8,                        \
            &Bs[tb_][(wave * 64 + g_ * 16) * 32]);                           \
    }                                                                        \
  }
#define SGA(sl_, ks_)                                                        \
  {                                                                          \
    if (wave < 4) {                                                          \
      int k0_ = (ks_) * 32;                                                  \
      int row_ = wave * 16 + r_in;                                           \
      dma16(asrc + ((size_t)(mrow0 + row_) << 10) + a_off + k0_ + c_in * 8,  \
            &As[sl_][(wave * 16) * 32]);                                     \
    }                                                                        \
  }

  f32x4 acc[2][8];
#pragma unroll
  for (int mi = 0; mi < 2; ++mi)
#pragma unroll
    for (int ni = 0; ni < 8; ++ni) acc[mi][ni] = (f32x4){0.f, 0.f, 0.f, 0.f};

  // prologue: B(0) then A(0) then A(1); drain B(0),A(0); A(1) stays in flight
  SGB(0, 0) SGA(0, 0) SGA(1, 1)
  if (wave < 4) { asm volatile("s_waitcnt vmcnt(1)" ::: "memory"); }
  else          { asm volatile("s_waitcnt vmcnt(0)" ::: "memory"); }
  __builtin_amdgcn_s_barrier();
  // invariant at step entry: outstanding(wave<4) = {A(ks+1)}, (wave>=4) = {}

  for (int ks = 0; ks < 16; ++ks) {
    const int bb = ks & 1;
    const int ra = ks % 3;
    const int nb = (ks + 1 < 16) ? ks + 1 : 15;   // tail: dummy restage
    const int na = (ks + 2 < 16) ? ks + 2 : 15;
    SGB(bb ^ 1, nb)              // +4 (issued oldest-first after A(ks+1))
    SGA((ks + 2) % 3, na)        // +1 for waves 0-3
    bf16x8 a[2], b[8];
#pragma unroll
    for (int mi = 0; mi < 2; ++mi)
      a[mi] = *(const bf16x8*)&As[ra][(wm * 32 + mi * 16 + l15) * 32 + quad * 8];
#pragma unroll
    for (int ni = 0; ni < 8; ++ni)
      b[ni] = *(const bf16x8*)&Bs[bb][(wn * 128 + ni * 16 + l15) * 32 + quad * 8];
    asm volatile("s_waitcnt lgkmcnt(0)" ::: "memory");
    __builtin_amdgcn_sched_barrier(0);
    __builtin_amdgcn_s_setprio(1);
#pragma unroll
    for (int ni = 0; ni < 8; ++ni)
#pragma unroll
      for (int mi = 0; mi < 2; ++mi)
        acc[mi][ni] = __builtin_amdgcn_mfma_f32_16x16x32_bf16(a[mi], b[ni], acc[mi][ni], 0, 0, 0);
    __builtin_amdgcn_s_setprio(0);
    // drain A(ks+1) + B(ks+1); leave A(ks+2) in flight
    if (wave < 4) { asm volatile("s_waitcnt vmcnt(1)" ::: "memory"); }
    else          { asm volatile("s_waitcnt vmcnt(0)" ::: "memory"); }
    __builtin_amdgcn_s_barrier();
  }
#undef SGB
#undef SGA
  // drain the tail dummy so no in-flight LDS write can outlive this block
  asm volatile("s_waitcnt vmcnt(0)" ::: "memory");

  float bv[8];
#pragma unroll
  for (int ni = 0; ni < 8; ++ni) bv[ni] = bias[wn * 128 + ni * 16 + l15];

  if (mode == 1) {
    // Hid = relu(acc + be1) -> bf16 second half of own row regions
#pragma unroll
    for (int mi = 0; mi < 2; ++mi)
#pragma unroll
      for (int ni = 0; ni < 8; ++ni)
#pragma unroll
        for (int reg = 0; reg < 4; ++reg) {
          int col = wn * 128 + ni * 16 + l15;
          int row = mrow0 + wm * 32 + mi * 16 + quad * 4 + reg;
          float h = acc[mi][ni][reg] + bv[ni];
          h = h > 0.f ? h : 0.f;
          hid[((size_t)row << 10) + 512 + col] = f2bf(h);
        }
  } else {
    // out = (acc + be2) with (wrep==0) mask -> fp32 full row, in place
#pragma unroll
    for (int mi = 0; mi < 2; ++mi)
#pragma unroll
      for (int ni = 0; ni < 8; ++ni)
#pragma unroll
        for (int reg = 0; reg < 4; ++reg) {
          int col = wn * 128 + ni * 16 + l15;
          int row = mrow0 + wm * 32 + mi * 16 + quad * 4 + reg;
          float o = acc[mi][ni][reg] + bv[ni];
          unsigned char m8 = mb[((size_t)row << 6) + (col >> 3)];
          outp[((size_t)row << 9) + col] = ((m8 >> (col & 7)) & 1) ? 0.f : o;
        }
  }
}

// ---------------------------------------------------------------- diag (hostcode only)
__global__ void k_diag(float* __restrict__ out, int hostcode) {
  if (hostcode != 0) out[0] = (float)hostcode;
}

// ---------------------------------------------------------------- launch
extern "C" void kernel_launch(void* const* d_in, const int* in_sizes, int n_in,
                              void* d_out, int out_size, void* d_ws, size_t ws_size,
                              hipStream_t stream) {
  const float* seg  = (const float*)d_in[0];
  const float* mask = (const float*)d_in[1];
  const float* W1   = (const float*)d_in[2];
  const float* b1   = (const float*)d_in[3];
  const float* W2   = (const float*)d_in[4];
  const float* We1  = (const float*)d_in[5];
  const float* be1  = (const float*)d_in[6];
  const float* We2  = (const float*)d_in[7];
  const float* be2  = (const float*)d_in[8];

  const size_t NROW = (size_t)BB * NN;            // 32768
  float* ws = (float*)d_ws;
  float* S0     = ws;                             // partial S, nblk=0
  float* S1     = S0 + NROW;                      // partial S, nblk=1
  int*   assign = (int*)(S1 + NROW);
  float* weight = (float*)(assign + NROW);
  float* total  = weight + NROW;
  int*   startn = (int*)(total + NROW);
  int*   endn   = startn + NROW;
  u16*   w1h    = (u16*)(endn + NROW);            // [n=512][k=1024]
  u16*   w1l    = w1h + (size_t)512 * 1024;
  u16*   we1t   = w1l + (size_t)512 * 1024;       // [n=512][k=512]
  u16*   we2t   = we1t + (size_t)512 * 512;       // end ~4.8 MB

  float* out = (float*)d_out;
  u16*   ahi = (u16*)d_out;                       // A hi plane (33.5 MB)
  u16*   alo = ahi + (size_t)NROW * HH;           // A lo plane (33.5 MB)
  u16*   hrep = (u16*)d_out;                      // wrep bf16 + Hid bf16 rows
  unsigned char* mbuf = (unsigned char*)w1h;      // 2 MB mask (w1h+w1l dead)

  int hostcode = 0;
  if (ws_size < (size_t)7 * NROW * 4 + (size_t)3 * 1024 * 1024) hostcode += 32768;
  if (out_size != 16777216) hostcode += 8192;

  k_prep_a<<<dim3(BB * NN / 4), dim3(256), 0, stream>>>(seg, ahi, alo);
  k_tr3   <<<dim3(8, 16, 3), dim3(256), 0, stream>>>(W1, We1, We2, w1h, w1l, we1t, we2t);
  k_sgemm <<<dim3(256), dim3(512), 0, stream>>>(ahi, alo, w1h, w1l, b1, W2, S0);
  k_row   <<<dim3(BB), dim3(256), 0, stream>>>(S0, S1, mask, assign, weight, total, startn, endn);
  k_pool  <<<dim3(BB * NN), dim3(64), 0, stream>>>(seg, assign, weight, total, startn, endn, hrep, mbuf);
  k_g     <<<dim3(512), dim3(512), 0, stream>>>(hrep, we1t, be1, mbuf, out, hrep, 0,   1);
  k_g     <<<dim3(512), dim3(512), 0, stream>>>(hrep, we2t, be2, mbuf, out, hrep, 512, 2);
  k_diag  <<<dim3(1), dim3(1), 0, stream>>>(out, hostcode);
}